// Round 6
// baseline (276.370 us; speedup 1.0000x reference)
//
#include <hip/hip_runtime.h>
#include <hip/hip_bf16.h>
#include <stdint.h>

// Fastfood 2D conv, MI355X. fp32 I/O:
// input (16,256,32,32), B/G/S (1,4096), bias (512), P (4096) i32 -> out (16,512,32,32).
// Per pixel: patch j=kk*256+ch (2304, pad 4096), *B, FWHT4096, perm P, *G, FWHT4096,
// *S[0:512]+bias.
//
// R6: pre-pass NCHW f32 -> NHWC bf16 (d_ws). Main kernel: block = (b, oh, half-row),
// grid 1024, 8 pixel-pairs per block. FWHT = 3x radix-16 with double-buffered
// swizzled LDS exchange (5 barriers/PROC, addresses precomputed in VGPRs).
// Patch loads coalesced u16, SOFTWARE-PIPELINED one PROC ahead (latency covered).
// LDS = 32 KB exchange + 16 KB accum = 48 KB -> 3 blocks/CU. Row halves mapped to
// the same XCD (g and g^8) so their 64 B out-stores merge in L2.

__device__ __forceinline__ float bf2f(uint16_t u) {
    union { uint32_t i; float f; } c; c.i = ((uint32_t)u) << 16; return c.f;
}
__device__ __forceinline__ uint16_t f2bf(float f) {  // RNE
    uint32_t u = __float_as_uint(f);
    return (uint16_t)((u + 0x7FFFu + ((u >> 16) & 1u)) >> 16);
}
__device__ __forceinline__ int swz(int j) {
    return j ^ ((j >> 5) & 7) ^ (((j >> 8) & 1) * 24) ^ (((j >> 9) & 1) * 8);
}
__device__ __forceinline__ uint32_t pk2(float a, float b) {
    __hip_bfloat162 h = __float22bfloat162_rn(make_float2(a, b));
    union { __hip_bfloat162 h; uint32_t u; } c; c.h = h; return c.u;
}
__device__ __forceinline__ float2 unpk(uint32_t u) {
    return make_float2(__uint_as_float(u << 16), __uint_as_float(u & 0xFFFF0000u));
}
__device__ __forceinline__ void h16p(float2* x) {
    #pragma unroll
    for (int h = 1; h < 16; h <<= 1) {
        #pragma unroll
        for (int g = 0; g < 16; g += 2 * h) {
            #pragma unroll
            for (int u = g; u < g + h; ++u) {
                float2 a = x[u], b = x[u + h];
                x[u]     = make_float2(a.x + b.x, a.y + b.y);  // v_pk_add_f32
                x[u + h] = make_float2(a.x - b.x, a.y - b.y);
            }
        }
    }
}

#define STW(abyte, off, w) \
    (*reinterpret_cast<uint32_t*>(reinterpret_cast<char*>(lds) + (abyte) + (off)) = (w))
#define LDW(abyte, off) \
    (*reinterpret_cast<const uint32_t*>(reinterpret_cast<const char*>(lds) + (abyte) + (off)))

// 12 guarded coalesced u16 loads for pair qq (cols 2qq-1..2qq+2, rows oh-1..oh+1).
// Conditions are wave-uniform (iw/ih uniform) -> cheap scalar branches.
#define LOADPAIR(qq, dst)                                                          \
{                                                                                  \
    const int c0 = ow0 + 2 * (qq) - 1;                                             \
    _Pragma("unroll")                                                              \
    for (int kh = 0; kh < 3; ++kh) {                                               \
        const uint16_t* pb = rT[kh] + (ptrdiff_t)c0 * 256;                         \
        _Pragma("unroll")                                                          \
        for (int cc = 0; cc < 4; ++cc) {                                           \
            const int iw = c0 + cc;                                                \
            (dst)[kh * 4 + cc] = (okk[kh] && (unsigned)iw < 32u)                   \
                                     ? pb[cc * 256] : (uint16_t)0;                 \
        }                                                                          \
    }                                                                              \
}

// One pixel pair q = 2m+PAR (pixels ow0+2q, ow0+2q+1). Exchange buffers alternate
// by parity as immediate byte offsets. CUR holds this pair's 12 patch taps;
// prefetches pair q+1 into NXT before the barrier chain.
#define PROC(PAR, CUR, NXT)                                                        \
{                                                                                  \
    const int q = 2 * m + (PAR);                                                   \
    constexpr int OA = (PAR) * 16384, OB = (1 - (PAR)) * 16384;                    \
    if (q < 7) LOADPAIR(q + 1, NXT)                                                \
    float2 x[16];                                                                  \
    _Pragma("unroll")                                                              \
    for (int kh = 0; kh < 3; ++kh) {                                               \
        _Pragma("unroll")                                                          \
        for (int kw = 0; kw < 3; ++kw)                                             \
            x[kh * 3 + kw] = make_float2(                                          \
                bf2f((CUR)[kh * 4 + kw])     * Bv[kh * 3 + kw],                    \
                bf2f((CUR)[kh * 4 + kw + 1]) * Bv[kh * 3 + kw]);                   \
    }                                                                              \
    _Pragma("unroll")                                                              \
    for (int r = 9; r < 16; ++r) x[r] = make_float2(0.f, 0.f);                     \
    h16p(x);                                          /* pass0 round A */          \
    _Pragma("unroll")                                                              \
    for (int r = 0; r < 16; ++r) STW(aA[r], OA, pk2(x[r].x, x[r].y));              \
    __syncthreads();                                                               \
    _Pragma("unroll")                                                              \
    for (int r = 0; r < 16; ++r) x[r] = unpk(LDW(aB[r], OA));                      \
    h16p(x);                                          /* round B */                \
    _Pragma("unroll")                                                              \
    for (int r = 0; r < 16; ++r) STW(aB[r], OB, pk2(x[r].x, x[r].y));              \
    __syncthreads();                                                               \
    _Pragma("unroll")                                                              \
    for (int r = 0; r < 16; ++r) x[r] = unpk(LDW(aC[r], OB));                      \
    h16p(x);                                          /* round C */                \
    _Pragma("unroll")                                                              \
    for (int r = 0; r < 16; ++r) STW(aC[r], OA, pk2(x[r].x, x[r].y));              \
    __syncthreads();                                                               \
    _Pragma("unroll")                                                              \
    for (int r = 0; r < 16; ++r) {                    /* perm + G -> A layout */   \
        float2 v = unpk(LDW(PA[r], OA));                                           \
        x[r] = make_float2(Gv[r] * v.x, Gv[r] * v.y);                              \
    }                                                                              \
    h16p(x);                                          /* pass1 round A */          \
    _Pragma("unroll")                                                              \
    for (int r = 0; r < 16; ++r) STW(aA[r], OB, pk2(x[r].x, x[r].y));              \
    __syncthreads();                                                               \
    _Pragma("unroll")                                                              \
    for (int r = 0; r < 16; ++r) x[r] = unpk(LDW(aB[r], OB));                      \
    h16p(x);                                          /* round B */                \
    _Pragma("unroll")                                                              \
    for (int r = 0; r < 16; ++r) STW(aB[r], OA, pk2(x[r].x, x[r].y));              \
    __syncthreads();                                                               \
    _Pragma("unroll")                                                              \
    for (int r = 0; r < 16; ++r) x[r] = unpk(LDW(aC[r], OA));                      \
    h16p(x);                                          /* round C: j = 16t + r */   \
    if (t < 32) {                                     /* S*x+bias -> accum[q] */   \
        const int qb = 8192 + 512 * q;                                             \
        _Pragma("unroll")                                                          \
        for (int r = 0; r < 16; ++r)                                               \
            lds[qb + epiW[r]] =                                                    \
                pk2(Sv[r] * x[r].x + Cv[r], Sv[r] * x[r].y + Cv[r]);               \
    }                                                                              \
}

__global__ __launch_bounds__(256, 3)
void fastfood_kernel(const uint16_t* __restrict__ inT,   // (b,h,w,c) bf16
                     const float* __restrict__ Bm,
                     const float* __restrict__ Gm,
                     const float* __restrict__ Sm,
                     const float* __restrict__ bias,
                     const int* __restrict__ P,
                     float* __restrict__ out)
{
    // [0,4096): exchange buf0 | [4096,8192): buf1 | [8192,12288): accum (8 pairs)
    __shared__ uint32_t lds[12288];   // 48 KiB -> 3 blocks/CU

    const int t  = threadIdx.x;
    const int t1 = t >> 4, t0 = t & 15;
    // g = (b<<6)|((oh>>3)<<4)|(half<<3)|(oh&7): row-halves are g and g^8 -> same XCD
    const int g    = blockIdx.x;
    const int half = (g >> 3) & 1;
    const int oh   = (((g >> 4) & 3) << 3) | (g & 7);
    const int b    = g >> 6;
    const int ow0  = half * 16;

    // ---- precomputed LDS byte addresses (loop-invariant, live in VGPRs)
    int aA[16], aB[16], aC[16], PA[16];
    float Gv[16];
    #pragma unroll
    for (int r = 0; r < 16; ++r) {
        aA[r] = swz(256 * r + t) * 4;
        aB[r] = swz(256 * t1 + 16 * r + t0) * 4;
        aC[r] = swz(256 * t1 + 16 * t0 + r) * 4;
        PA[r] = swz(P[r * 256 + t]) * 4;
        Gv[r] = Gm[r * 256 + t];
    }
    float Bv[9];
    #pragma unroll
    for (int r = 0; r < 9; ++r) Bv[r] = Bm[r * 256 + t];
    float Sv[16], Cv[16];
    if (t < 32) {
        #pragma unroll
        for (int r = 0; r < 16; ++r) { Sv[r] = Sm[16 * t + r]; Cv[r] = bias[16 * t + r]; }
    }
    int epiW[16];
    #pragma unroll
    for (int r = 0; r < 16; ++r) epiW[r] = 16 * t + (r ^ ((t >> 1) & 7));

    // ---- patch row pointers in NHWC bf16, channel = t
    const uint16_t* rT[3]; bool okk[3];
    #pragma unroll
    for (int kh = 0; kh < 3; ++kh) {
        const int ih = oh - 1 + kh;
        okk[kh] = (unsigned)ih < 32u;
        rT[kh]  = inT + ((size_t)(b * 32 + ih) * 32) * 256 + t;
    }

    uint16_t bufE[12], bufO[12];      // pipelined patch taps (even/odd PROC)
    LOADPAIR(0, bufE)

    #pragma unroll 1
    for (int m = 0; m < 4; ++m) {
        PROC(0, bufE, bufO)
        PROC(1, bufO, bufE)
    }

    // ---- flush: thread t -> channels 2t, 2t+1; 16 px x 512 ch (64 B per channel)
    __syncthreads();
    {
        const int oc0 = 2 * t, oc1 = 2 * t + 1;
        const int c0 = (oc0 & ~15) | ((oc0 & 15) ^ ((oc0 >> 5) & 7));
        const int c1 = (oc1 & ~15) | ((oc1 & 15) ^ ((oc1 >> 5) & 7));
        float r0[16], r1[16];
        #pragma unroll
        for (int qq = 0; qq < 8; ++qq) {
            float2 va = unpk(lds[8192 + 512 * qq + c0]);
            float2 vb = unpk(lds[8192 + 512 * qq + c1]);
            r0[2 * qq] = va.x; r0[2 * qq + 1] = va.y;
            r1[2 * qq] = vb.x; r1[2 * qq + 1] = vb.y;
        }
        float* o0 = out + ((size_t)(b * 512 + oc0) * 1024 + oh * 32 + ow0);
        float* o1 = o0 + 1024;
        #pragma unroll
        for (int gg = 0; gg < 4; ++gg) {
            *reinterpret_cast<float4*>(o0 + 4 * gg) =
                make_float4(r0[4 * gg], r0[4 * gg + 1], r0[4 * gg + 2], r0[4 * gg + 3]);
            *reinterpret_cast<float4*>(o1 + 4 * gg) =
                make_float4(r1[4 * gg], r1[4 * gg + 1], r1[4 * gg + 2], r1[4 * gg + 3]);
        }
    }
}

// NCHW f32 -> NHWC bf16, LDS-bounced, coalesced both directions.
__global__ __launch_bounds__(256)
void transpose_in(const float* __restrict__ in, uint16_t* __restrict__ inT)
{
    __shared__ uint16_t ldt[256 * 33];   // +1 halfword pad per channel row
    const int t = threadIdx.x;
    const int b = blockIdx.x >> 5, h = blockIdx.x & 31;

    #pragma unroll
    for (int i = 0; i < 8; ++i) {
        const int idx = t + i * 256;         // 2048 16-byte chunks
        const int part = idx & 7, c = idx >> 3;
        float4 v = *reinterpret_cast<const float4*>(
            in + ((size_t)(b * 256 + c) * 1024 + h * 32 + part * 4));
        const int a = c * 33 + part * 4;
        ldt[a]     = f2bf(v.x); ldt[a + 1] = f2bf(v.y);
        ldt[a + 2] = f2bf(v.z); ldt[a + 3] = f2bf(v.w);
    }
    __syncthreads();

    const int c0 = 2 * (t & 127);
    const int wbase = (t >> 7) * 16;
    uint32_t* outw = reinterpret_cast<uint32_t*>(inT + (size_t)(b * 32 + h) * 32 * 256);
    #pragma unroll
    for (int i = 0; i < 16; ++i) {
        const int w = wbase + i;
        const uint32_t lo = ldt[c0 * 33 + w];
        const uint32_t hi = ldt[(c0 + 1) * 33 + w];
        outw[(w * 256 + c0) >> 1] = lo | (hi << 16);
    }
}

extern "C" void kernel_launch(void* const* d_in, const int* in_sizes, int n_in,
                              void* d_out, int out_size, void* d_ws, size_t ws_size,
                              hipStream_t stream) {
    const float* in   = (const float*)d_in[0];
    const float* Bm   = (const float*)d_in[1];
    const float* Gm   = (const float*)d_in[2];
    const float* Sm   = (const float*)d_in[3];
    const float* bias = (const float*)d_in[4];
    const int*   P    = (const int*)d_in[5];
    float*    out = (float*)d_out;
    uint16_t* inT = (uint16_t*)d_ws;      // 16 MB NHWC bf16 staging

    transpose_in<<<dim3(512), dim3(256), 0, stream>>>(in, inT);
    fastfood_kernel<<<dim3(1024), dim3(256), 0, stream>>>(inT, Bm, Gm, Sm, bias, P, out);
}

// Round 7
// 250.929 us; speedup vs baseline: 1.1014x; 1.1014x over previous
//
#include <hip/hip_runtime.h>
#include <hip/hip_bf16.h>
#include <stdint.h>

// Fastfood 2D conv, MI355X. fp32 I/O:
// input (16,256,32,32), B/G/S (1,4096), bias (512), P (4096) i32 -> out (16,512,32,32).
// Per pixel: patch j=kk*256+ch (2304, pad 4096), *B, FWHT4096, perm P, *G, FWHT4096,
// *S[0:512]+bias.
//
// R7: WAVE-AUTONOMOUS FWHT — zero barriers. FWHT4096 = H64(hi digit) x H64(lo digit).
// One wave per pixel: 64 fp32 values/lane as 32 float2 (v_pk_add_f32 butterflies).
// Transposes via a wave-PRIVATE 16KB LDS region (4 waves x 16KB = 64KB exactly);
// within-wave RAW ordering needs only lgkmcnt (compiler-inserted) — no __syncthreads.
// Storage convention: value[j] lives at word sig(j) = j ^ ((j>>6)&31) (low-5 XOR):
//   A-pattern (j=64r+l) and B-pattern (j=64l+r) accesses are both exactly 2 lanes/bank.
// B-pattern addr = A-pattern addr + lane-const -> one 32-reg address array.
// Perm gathers straight into B-layout; FWHT#2 runs lo-digit-first so it ENDS in
// A-layout: every lane holds 8 output channels oc=64k+l -> coalesced 256B stores to
// pixel-major ws; transpose_out (proven R3) emits channel-major NCHW.

typedef float v2f __attribute__((ext_vector_type(2)));

__device__ __forceinline__ float bf2f(uint16_t u) {
    union { uint32_t i; float f; } c; c.i = ((uint32_t)u) << 16; return c.f;
}
__device__ __forceinline__ uint16_t f2bf(float f) {  // RNE
    uint32_t u = __float_as_uint(f);
    return (uint16_t)((u + 0x7FFFu + ((u >> 16) & 1u)) >> 16);
}
__device__ __forceinline__ uint32_t pkbf(float a, float b) {
    return (uint32_t)f2bf(a) | ((uint32_t)f2bf(b) << 16);
}
__device__ __forceinline__ v2f unpk(uint32_t u) {
    v2f r; r.x = __uint_as_float(u << 16); r.y = __uint_as_float(u & 0xFFFF0000u);
    return r;
}
__device__ __forceinline__ int sigw(int j) {         // word index of value j
    return (j & ~63) | ((j & 63) ^ ((j >> 6) & 31));
}

// In-register H64 over the 64 values (r = 2p + half). 160 pk + 64 scalar ops.
__device__ __forceinline__ void h64(v2f* x) {
    #pragma unroll
    for (int hh = 1; hh < 32; hh <<= 1) {
        #pragma unroll
        for (int g = 0; g < 32; g += 2 * hh) {
            #pragma unroll
            for (int u = g; u < g + hh; ++u) {
                v2f a = x[u], c = x[u + hh];
                x[u] = a + c; x[u + hh] = a - c;     // v_pk_add_f32 (+neg)
            }
        }
    }
    #pragma unroll
    for (int p = 0; p < 32; ++p) {                   // stage h=1 (intra-reg)
        float s = x[p].x + x[p].y, d = x[p].x - x[p].y;
        x[p].x = s; x[p].y = d;
    }
}

__global__ __launch_bounds__(256, 2)
void fastfood_kernel(const uint16_t* __restrict__ inT,   // (b,h,w,c) bf16
                     const float* __restrict__ Bm,
                     const float* __restrict__ Gm,
                     const float* __restrict__ Sm,
                     const float* __restrict__ bias,
                     const int* __restrict__ P,
                     float* __restrict__ pixout,         // (pix, 512) when !direct
                     float* __restrict__ out,            // direct fallback
                     int direct)
{
    __shared__ uint32_t lds4[16384];                 // 64 KiB; wave w: [16384w, +16384)
    char* lds = (char*)lds4;

    const int t = threadIdx.x, w = t >> 6, l = t & 63;
    const int b = blockIdx.x >> 5, oh = blockIdx.x & 31;
    const int wb = w << 14;                          // wave LDS byte base

    // A-pattern (j=64r+l): byte = addrA[r&31] + 256*r
    int addrA[32];
    #pragma unroll
    for (int k = 0; k < 32; ++k)
        addrA[k] = wb + ((l & 32) << 2) + (((l & 31) ^ k) << 2);
    // B-pattern (j=64l+r): byte = addrA[r&31] + cB + 128*(r>>5)
    const int cB = (l << 8) - ((l & 32) << 2);

    // constants (bf16x2-packed to fit VGPR budget)
    uint32_t Bp[18];
    #pragma unroll
    for (int p = 0; p < 18; ++p)
        Bp[p] = pkbf(Bm[128 * p + l], Bm[128 * p + 64 + l]);
    uint32_t Gp[32], PAp[32];
    #pragma unroll
    for (int p = 0; p < 32; ++p) {
        float2 g2 = *reinterpret_cast<const float2*>(Gm + 64 * l + 2 * p);
        Gp[p] = pkbf(g2.x, g2.y);
        int2 p2 = *reinterpret_cast<const int2*>(P + 64 * l + 2 * p);
        PAp[p] = (uint32_t)(wb + (sigw(p2.x) << 2))
               | ((uint32_t)(wb + (sigw(p2.y) << 2)) << 16);
    }
    float Sv[8], Cv[8];
    #pragma unroll
    for (int k = 0; k < 8; ++k) { Sv[k] = Sm[64 * k + l]; Cv[k] = bias[64 * k + l]; }

    const uint16_t* rT[3]; bool okk[3];
    #pragma unroll
    for (int kh = 0; kh < 3; ++kh) {
        const int ih = oh - 1 + kh;
        okk[kh] = (unsigned)ih < 32u;
        rT[kh] = inT + ((size_t)(b * 32 + ih) * 32) * 256 + l;
    }

    #pragma unroll 1
    for (int i = 0; i < 8; ++i) {                    // 8 pixels per wave, independent
        const int ow = (w << 3) + i;
        v2f x[32];
        float* xf = (float*)x;                       // xf[r] = value j = 64r + l

        // build layout A: r = 4kk + c2, ch = 64c2 + l (coalesced u16 taps), *B
        #pragma unroll
        for (int kh = 0; kh < 3; ++kh) {
            #pragma unroll
            for (int kw = 0; kw < 3; ++kw) {
                const int kk = kh * 3 + kw;
                const int iw = ow - 1 + kw;
                float v0 = 0.f, v1 = 0.f, v2 = 0.f, v3 = 0.f;
                if (okk[kh] && (unsigned)iw < 32u) {
                    const uint16_t* pp = rT[kh] + iw * 256;
                    v0 = bf2f(pp[0]);   v1 = bf2f(pp[64]);
                    v2 = bf2f(pp[128]); v3 = bf2f(pp[192]);
                }
                v2f bA = unpk(Bp[2 * kk]), bB = unpk(Bp[2 * kk + 1]);
                x[2 * kk].x     = v0 * bA.x; x[2 * kk].y     = v1 * bA.y;
                x[2 * kk + 1].x = v2 * bB.x; x[2 * kk + 1].y = v3 * bB.y;
            }
        }
        #pragma unroll
        for (int p = 18; p < 32; ++p) { x[p].x = 0.f; x[p].y = 0.f; }

        h64(x);                                      // H over hi digit (layout A)
        #pragma unroll
        for (int r = 0; r < 64; ++r)                 // T1 write (A-pattern)
            *(float*)(lds + addrA[r & 31] + 256 * r) = xf[r];
        #pragma unroll
        for (int r = 0; r < 64; ++r)                 // T1 read (B-pattern)
            xf[r] = *(const float*)(lds + (addrA[r & 31] + cB) + 128 * (r >> 5));
        h64(x);                                      // H over lo digit -> FWHT1 (B)

        #pragma unroll
        for (int r = 0; r < 64; ++r)                 // perm source write (B-pattern)
            *(float*)(lds + (addrA[r & 31] + cB) + 128 * (r >> 5)) = xf[r];
        #pragma unroll
        for (int p = 0; p < 32; ++p) {               // gather P + *G (lands in B)
            const int a0 = PAp[p] & 0xffff, a1 = PAp[p] >> 16;
            float g0 = *(const float*)(lds + a0);
            float g1 = *(const float*)(lds + a1);
            v2f gv = unpk(Gp[p]);
            x[p].x = g0 * gv.x; x[p].y = g1 * gv.y;
        }

        h64(x);                                      // H over lo digit (layout B)
        #pragma unroll
        for (int r = 0; r < 64; ++r)                 // T2 write (B-pattern)
            *(float*)(lds + (addrA[r & 31] + cB) + 128 * (r >> 5)) = xf[r];
        #pragma unroll
        for (int r = 0; r < 64; ++r)                 // T2 read (A-pattern)
            xf[r] = *(const float*)(lds + addrA[r & 31] + 256 * r);
        h64(x);                                      // H over hi digit -> FWHT2 (A)

        // epilogue: xf[k] = value j = 64k + l, k<8 covers oc = 0..511 on all lanes
        const int pix = (b * 32 + oh) * 32 + ow;
        if (!direct) {
            #pragma unroll
            for (int k = 0; k < 8; ++k)              // coalesced 256B stores
                pixout[(size_t)pix * 512 + 64 * k + l] = Sv[k] * xf[k] + Cv[k];
        } else {
            #pragma unroll
            for (int k = 0; k < 8; ++k)              // slow fallback (ws too small)
                out[((size_t)(b * 512 + 64 * k + l)) * 1024 + oh * 32 + ow]
                    = Sv[k] * xf[k] + Cv[k];
        }
    }
}

// NCHW f32 -> NHWC bf16, LDS-bounced, coalesced both directions. (proven R5)
__global__ __launch_bounds__(256)
void transpose_in(const float* __restrict__ in, uint16_t* __restrict__ inT)
{
    __shared__ uint16_t ldt[256 * 33];
    const int t = threadIdx.x;
    const int b = blockIdx.x >> 5, h = blockIdx.x & 31;

    #pragma unroll
    for (int i = 0; i < 8; ++i) {
        const int idx = t + i * 256;
        const int part = idx & 7, c = idx >> 3;
        float4 v = *reinterpret_cast<const float4*>(
            in + ((size_t)(b * 256 + c) * 1024 + h * 32 + part * 4));
        const int a = c * 33 + part * 4;
        ldt[a]     = f2bf(v.x); ldt[a + 1] = f2bf(v.y);
        ldt[a + 2] = f2bf(v.z); ldt[a + 3] = f2bf(v.w);
    }
    __syncthreads();

    const int c0 = 2 * (t & 127);
    const int wbase = (t >> 7) * 16;
    uint32_t* outw = reinterpret_cast<uint32_t*>(inT + (size_t)(b * 32 + h) * 32 * 256);
    #pragma unroll
    for (int i = 0; i < 16; ++i) {
        const int ww = wbase + i;
        const uint32_t lo = ldt[c0 * 33 + ww];
        const uint32_t hi = ldt[(c0 + 1) * 33 + ww];
        outw[(ww * 256 + c0) >> 1] = lo | (hi << 16);
    }
}

// ws (b,oh,ow,oc) -> out (b,oc,oh,ow). Per-lane 128B channel rows. (proven R3)
__global__ __launch_bounds__(256)
void transpose_out(const float* __restrict__ ws, float* __restrict__ out)
{
    const int t  = threadIdx.x;
    const int b  = blockIdx.x >> 5;
    const int oh = blockIdx.x & 31;
    const float* src = ws + (size_t)((b * 32 + oh) * 32) * 512;
    #pragma unroll
    for (int c = 0; c < 2; ++c) {
        const int oc = 2 * t + c;
        float* dst = out + ((size_t)b * 512 + oc) * 1024 + oh * 32;
        #pragma unroll
        for (int g = 0; g < 8; ++g) {
            float4 v;
            v.x = src[(4 * g + 0) * 512 + oc];
            v.y = src[(4 * g + 1) * 512 + oc];
            v.z = src[(4 * g + 2) * 512 + oc];
            v.w = src[(4 * g + 3) * 512 + oc];
            *reinterpret_cast<float4*>(dst + 4 * g) = v;
        }
    }
}

extern "C" void kernel_launch(void* const* d_in, const int* in_sizes, int n_in,
                              void* d_out, int out_size, void* d_ws, size_t ws_size,
                              hipStream_t stream) {
    const float* in   = (const float*)d_in[0];
    const float* Bm   = (const float*)d_in[1];
    const float* Gm   = (const float*)d_in[2];
    const float* Sm   = (const float*)d_in[3];
    const float* bias = (const float*)d_in[4];
    const int*   P    = (const int*)d_in[5];
    float* out = (float*)d_out;

    const size_t inT_bytes = (size_t)16 * 32 * 32 * 256 * 2;          // 8 MB
    const size_t pix_bytes = (size_t)16 * 32 * 32 * 512 * 4;          // 33.5 MB
    uint16_t* inT = (uint16_t*)d_ws;
    float* pixout = (float*)((char*)d_ws + inT_bytes);
    const int direct = (ws_size < inT_bytes + pix_bytes) ? 1 : 0;

    transpose_in<<<dim3(512), dim3(256), 0, stream>>>(in, inT);
    fastfood_kernel<<<dim3(512), dim3(256), 0, stream>>>(inT, Bm, Gm, Sm, bias, P,
                                                         pixout, out, direct);
    if (!direct)
        transpose_out<<<dim3(512), dim3(256), 0, stream>>>(pixout, out);
}